// Round 1
// baseline (744.643 us; speedup 1.0000x reference)
//
#include <hip/hip_runtime.h>
#include <math.h>

#define V        8192
#define NTOK     16384          // B*T = 8*2048
#define CWIDTH   32             // columns per bucket
#define NBUCKET  (V / CWIDTH)   // 256
#define JTILE    256            // output rows (j) per scatter block
#define NJT      (V / JTILE)    // 32
#define CAP      1024           // max tokens per bucket (mean 64, std ~8 -> huge margin)

// ws layout:
//   [0,    1024) : int counts[NBUCKET]
//   [2048, 2056) : double loss_sum
//   [2056, 2060) : int valid_count
//   [4096, 4096 + NBUCKET*CAP*4)           : int bins (packed (i<<13)|c)  1 MiB
//   [BINS_END, +V*NJT*4)                   : float pm_g  (per-(jtile,col) partial max)  1 MiB
//   [.., +V*NJT*4)                         : float ps_g  (per-(jtile,col) partial sumexp) 1 MiB
//   lse[V] overlays the bins region (bins are dead once scatter completes)
#define BINS_OFF  4096
#define BINS_SZ   (NBUCKET * CAP * 4)
#define PM_OFF    (BINS_OFF + BINS_SZ)
#define PS_OFF    (PM_OFF + V * NJT * 4)
#define LSE_OFF   BINS_OFF            // overlay: written by merge (after scatter), read by loss

__global__ __launch_bounds__(256) void zero_ws_kernel(int* counts, double* loss_sum,
                                                      int* valid_count) {
    counts[threadIdx.x] = 0;
    if (threadIdx.x == 0) { *loss_sum = 0.0; *valid_count = 0; }
}

__global__ __launch_bounds__(256) void bin_kernel(const int* __restrict__ idx,
                                                  int* __restrict__ counts,
                                                  int* __restrict__ bins) {
    int i = blockIdx.x * 256 + threadIdx.x;
    if (i >= NTOK) return;
    int c = idx[i];
    int bucket = c >> 5;
    int pos = atomicAdd(&counts[bucket], 1);
    if (pos < CAP) bins[bucket * CAP + pos] = (i << 13) | c;
}

// One block per (bucket, j-tile). Loads W[j0:j0+256][c0:c0+32] coalesced into
// padded LDS, writes a coalesced 256-float logits segment per token in the
// bucket, then computes per-column partial log-softmax stats (max + sumexp
// over the 256 rows of the tile) from the SAME tile — zero extra HBM traffic.
__global__ __launch_bounds__(256) void scatter_kernel(const float* __restrict__ W,
                                                      const float* __restrict__ bias,
                                                      const int* __restrict__ counts,
                                                      const int* __restrict__ bins,
                                                      float* __restrict__ out,
                                                      float* __restrict__ pm_g,
                                                      float* __restrict__ ps_g) {
    __shared__ float lds[JTILE * 33];   // pitch 33 -> bank = (row + col) % 32, conflict-free
    __shared__ float sbias[JTILE];
    __shared__ float spm[256];
    __shared__ float sps[256];
    const int tid = threadIdx.x;
    const int bucket = blockIdx.x;
    const int c0 = bucket * CWIDTH;
    const int jt = blockIdx.y;
    const int j0 = jt * JTILE;

    // Tile load: 256 threads, 8 float4 each. cg = col-group (8 x float4 = 32 cols).
    const int cg = tid & 7;
    const int rb = tid >> 3;
    #pragma unroll
    for (int m = 0; m < 8; ++m) {
        int r = rb + 32 * m;
        const float4 v = *(const float4*)(&W[(size_t)(j0 + r) * V + c0 + 4 * cg]);
        float* p = &lds[r * 33 + 4 * cg];
        p[0] = v.x; p[1] = v.y; p[2] = v.z; p[3] = v.w;
    }
    const float bj = bias[j0 + tid];
    sbias[tid] = bj;
    __syncthreads();

    // ---- token scatter (coalesced 1 KiB stores), unrolled x4 for ILP ----
    int n = counts[bucket];
    if (n > CAP) n = CAP;
    const int* mybin = &bins[bucket * CAP];
    int t = 0;
    for (; t + 3 < n; t += 4) {
        int e0 = mybin[t], e1 = mybin[t + 1], e2 = mybin[t + 2], e3 = mybin[t + 3];
        float x0 = lds[tid * 33 + ((e0 & (V - 1)) - c0)] + bj;
        float x1 = lds[tid * 33 + ((e1 & (V - 1)) - c0)] + bj;
        float x2 = lds[tid * 33 + ((e2 & (V - 1)) - c0)] + bj;
        float x3 = lds[tid * 33 + ((e3 & (V - 1)) - c0)] + bj;
        out[(size_t)(e0 >> 13) * V + j0 + tid] = x0;
        out[(size_t)(e1 >> 13) * V + j0 + tid] = x1;
        out[(size_t)(e2 >> 13) * V + j0 + tid] = x2;
        out[(size_t)(e3 >> 13) * V + j0 + tid] = x3;
    }
    for (; t < n; ++t) {
        int e = mybin[t];
        out[(size_t)(e >> 13) * V + j0 + tid] = lds[tid * 33 + ((e & (V - 1)) - c0)] + bj;
    }

    // ---- per-column partial softmax stats over this tile's 256 rows ----
    // thread (cc, rg): column cc, row-group rg covering rows rg*32 .. rg*32+31.
    // LDS read bank = (r*33 + cc) % 32 = (k + cc) % 32 within a 32-lane group:
    // conflict-free (2-way across the wave's two row-groups, which is free).
    const int cc = tid & 31;
    const int rg = tid >> 5;
    float pmax = -INFINITY;
    #pragma unroll
    for (int k = 0; k < 32; ++k) {
        int r = rg * 32 + k;
        pmax = fmaxf(pmax, lds[r * 33 + cc] + sbias[r]);
    }
    float psum = 0.f;
    #pragma unroll
    for (int k = 0; k < 32; ++k) {
        int r = rg * 32 + k;
        psum += expf(lds[r * 33 + cc] + sbias[r] - pmax);
    }
    spm[tid] = pmax;
    sps[tid] = psum;
    __syncthreads();

    if (tid < 32) {
        float M = spm[tid];
        #pragma unroll
        for (int p = 1; p < 8; ++p) M = fmaxf(M, spm[p * 32 + tid]);
        float S = 0.f;
        #pragma unroll
        for (int p = 0; p < 8; ++p) S += sps[p * 32 + tid] * expf(spm[p * 32 + tid] - M);
        pm_g[jt * V + c0 + tid] = M;
        ps_g[jt * V + c0 + tid] = S;
    }
}

// Merge the 32 per-jtile partials for each column c into lse[c] = m + log(s).
__global__ __launch_bounds__(256) void merge_kernel(const float* __restrict__ pm_g,
                                                    const float* __restrict__ ps_g,
                                                    float* __restrict__ lse) {
    const int c = blockIdx.x * 256 + threadIdx.x;
    float pm[NJT];
    float m = -INFINITY;
    #pragma unroll
    for (int jt = 0; jt < NJT; ++jt) {
        pm[jt] = pm_g[jt * V + c];
        m = fmaxf(m, pm[jt]);
    }
    float s = 0.f;
    #pragma unroll
    for (int jt = 0; jt < NJT; ++jt)
        s += ps_g[jt * V + c] * expf(pm[jt] - m);
    lse[c] = m + logf(s);
}

// One thread per token: nll = lse[idx[i]] - (W[tgt, idx[i]] + b[tgt]).
// No logits re-read — the 512 MiB out buffer is never touched again.
__global__ __launch_bounds__(256) void loss_kernel(const int* __restrict__ idx,
                                                   const int* __restrict__ targets,
                                                   const float* __restrict__ W,
                                                   const float* __restrict__ bias,
                                                   const float* __restrict__ lse,
                                                   double* __restrict__ loss_sum,
                                                   int* __restrict__ valid_count) {
    const int i = blockIdx.x * 256 + threadIdx.x;
    float nll = 0.f;
    int val = 0;
    if (i < NTOK) {
        int tgt = targets[i];
        if (tgt >= 0) {
            int c = idx[i];
            float lt = W[(size_t)tgt * V + c] + bias[tgt];
            nll = lse[c] - lt;
            val = 1;
        }
    }
    #pragma unroll
    for (int off = 32; off >= 1; off >>= 1) {
        nll += __shfl_xor(nll, off, 64);
        val += __shfl_xor(val, off, 64);
    }
    if ((threadIdx.x & 63) == 0 && val > 0) {
        atomicAdd(loss_sum, (double)nll);
        atomicAdd(valid_count, val);
    }
}

__global__ void finalize_kernel(const double* __restrict__ loss_sum,
                                const int* __restrict__ valid_count,
                                float* __restrict__ out) {
    int c = *valid_count;
    if (c < 1) c = 1;
    out[(size_t)NTOK * V] = (float)(*loss_sum / (double)c);
}

extern "C" void kernel_launch(void* const* d_in, const int* in_sizes, int n_in,
                              void* d_out, int out_size, void* d_ws, size_t ws_size,
                              hipStream_t stream) {
    const int*   idx     = (const int*)d_in[0];
    const int*   targets = (const int*)d_in[1];
    const float* W       = (const float*)d_in[2];
    const float* bias    = (const float*)d_in[3];
    float*       out     = (float*)d_out;

    char* ws = (char*)d_ws;
    int*    counts      = (int*)(ws);
    double* loss_sum    = (double*)(ws + 2048);
    int*    valid_count = (int*)(ws + 2056);
    int*    bins        = (int*)(ws + BINS_OFF);
    float*  pm_g        = (float*)(ws + PM_OFF);
    float*  ps_g        = (float*)(ws + PS_OFF);
    float*  lse         = (float*)(ws + LSE_OFF);   // overlays bins (dead after scatter)

    zero_ws_kernel<<<1, 256, 0, stream>>>(counts, loss_sum, valid_count);
    bin_kernel<<<NTOK / 256, 256, 0, stream>>>(idx, counts, bins);
    dim3 grid3(NBUCKET, NJT);
    scatter_kernel<<<grid3, 256, 0, stream>>>(W, bias, counts, bins, out, pm_g, ps_g);
    merge_kernel<<<V / 256, 256, 0, stream>>>(pm_g, ps_g, lse);
    loss_kernel<<<NTOK / 256, 256, 0, stream>>>(idx, targets, W, bias, lse,
                                                loss_sum, valid_count);
    finalize_kernel<<<1, 1, 0, stream>>>(loss_sum, valid_count, out);
}